// Round 1
// baseline (9628.992 us; speedup 1.0000x reference)
//
#include <hip/hip_runtime.h>
#include <hip/hip_bf16.h>

#define TT 24
#define FF 16
#define HH 64

// ---------------- utility ----------------
__global__ void k_zero(int* __restrict__ p, long n){
  long i = (long)blockIdx.x*blockDim.x + threadIdx.x;
  long st = (long)gridDim.x*blockDim.x;
  for(; i<n; i+=st) p[i]=0;
}

__global__ void k_deg(const int* __restrict__ ei, int E, int* __restrict__ deg){
  int i = blockIdx.x*blockDim.x + threadIdx.x;
  if(i<E) atomicAdd(&deg[ei[E+i]], 1);   // dst = ei[E+i]
}

__global__ void k_dinv(const int* __restrict__ deg, float* __restrict__ dinv, int N){
  int i = blockIdx.x*blockDim.x + threadIdx.x;
  if(i<N) dinv[i] = rsqrtf((float)deg[i] + 1.0f);
}

// exclusive prefix sum of deg -> offsets[0..N], single block of 1024
__global__ __launch_bounds__(1024) void k_scan(const int* __restrict__ deg, int* __restrict__ offsets, int N){
  __shared__ int s[1024];
  int tid = threadIdx.x;
  int CH = (N + 1023) >> 10;
  int lo = tid*CH, hi = min(N, lo+CH);
  int sum=0;
  for(int j=lo;j<hi;j++) sum += deg[j];
  s[tid]=sum; __syncthreads();
  for(int o=1;o<1024;o<<=1){
    int v = 0;
    if(tid>=o) v = s[tid-o];
    __syncthreads();
    s[tid] += v;
    __syncthreads();
  }
  int run = s[tid]-sum;                 // exclusive base for this chunk
  for(int j=lo;j<hi;j++){ offsets[j]=run; run += deg[j]; }
  if(tid==1023) offsets[N]=s[1023];
}

__global__ void k_fill(const int* __restrict__ ei, int E, const float* __restrict__ dinv,
                       const int* __restrict__ offsets, int* __restrict__ counters,
                       int* __restrict__ csr_src, float* __restrict__ csr_w){
  int i = blockIdx.x*blockDim.x + threadIdx.x;
  if(i>=E) return;
  int s = ei[i], d = ei[E+i];
  int slot = offsets[d] + atomicAdd(&counters[d], 1);
  csr_src[slot] = s;
  csr_w[slot]   = dinv[s]*dinv[d];
}

// M1[j*16+f] = sum_k gcn_w[f][k]*w_ih[j][k] ; c1[j] = b_ih[j] + sum_k gcn_b[k]*w_ih[j][k]
__global__ void k_m1(const float* __restrict__ gcn_w, const float* __restrict__ gcn_b,
                     const float* __restrict__ w_ih, const float* __restrict__ b_ih,
                     float* __restrict__ M1, float* __restrict__ c1){
  int tid = blockIdx.x*blockDim.x + threadIdx.x;
  if(tid < 192*FF){
    int j = tid >> 4, f = tid & 15;
    float s = 0.f;
    for(int k=0;k<HH;k++) s += gcn_w[f*HH+k]*w_ih[j*HH+k];
    M1[tid] = s;
  } else if (tid < 192*FF + 192){
    int j = tid - 192*FF;
    float s = b_ih[j];
    for(int k=0;k<HH;k++) s += gcn_b[k]*w_ih[j*HH+k];
    c1[j] = s;
  }
}

// aggregation in F-space for ALL t: agg[t][n][f] = self_norm[n]*x[t][n][f] + sum_in-edges norm*x[t][src][f]
// one wave per node; lane -> (f = lane&15, tq = lane>>4); 6 accumulators cover t = tq + 4k
__global__ __launch_bounds__(256)
void k_agg(const float* __restrict__ x, const int* __restrict__ offsets,
           const int* __restrict__ csr_src, const float* __restrict__ csr_w,
           const float* __restrict__ dinv, float* __restrict__ agg, int N){
  int wid = (blockIdx.x*blockDim.x + threadIdx.x) >> 6;
  if(wid >= N) return;
  int lane = threadIdx.x & 63;
  int f = lane & 15, tq = lane >> 4;
  const int n = wid;
  size_t NF = (size_t)N*FF;
  float sn = dinv[n]; sn *= sn;
  float acc[6];
  #pragma unroll
  for(int k=0;k<6;k++){
    int t = tq + 4*k;
    acc[k] = sn * x[(size_t)t*NF + (size_t)n*FF + f];
  }
  int lo = offsets[n], hi = offsets[n+1];
  for(int j=lo;j<hi;j++){
    int s = csr_src[j];
    float wgt = csr_w[j];
    size_t base = (size_t)s*FF + f;
    #pragma unroll
    for(int k=0;k<6;k++){
      int t = tq + 4*k;
      acc[k] += wgt * x[(size_t)t*NF + base];
    }
  }
  #pragma unroll
  for(int k=0;k<6;k++){
    int t = tq + 4*k;
    agg[(size_t)t*NF + (size_t)n*FF + f] = acc[k];
  }
}

// one GRU timestep. block = 256 = 4 waves; wave w handles channel tile [w*16, w*16+16)
// for the block's 64 nodes (lane = node-in-block). Weights read wave-uniformly (scalarizable).
__global__ __launch_bounds__(256)
void k_gru(const float* __restrict__ aggt, const float* __restrict__ M1, const float* __restrict__ c1,
           const float* __restrict__ w_hh, const float* __restrict__ b_hh,
           const float* __restrict__ hin, float* __restrict__ hout, int N)
{
  const int wave = threadIdx.x >> 6;
  const int lane = threadIdx.x & 63;
  const int node = blockIdx.x*64 + lane;
  const bool act = node < N;
  const int c0 = wave*16;

  float a[FF];
  {
    const float4* ap = (const float4*)(aggt + (size_t)node*FF);
    #pragma unroll
    for(int q=0;q<4;q++){
      float4 v = act ? ap[q] : make_float4(0.f,0.f,0.f,0.f);
      a[4*q+0]=v.x; a[4*q+1]=v.y; a[4*q+2]=v.z; a[4*q+3]=v.w;
    }
  }

  float ar[16],az[16],an[16],br[16],bz[16],bn[16];
  #pragma unroll
  for(int c=0;c<16;c++){
    int j=c0+c;
    ar[c]=c1[j]; az[c]=c1[j+64]; an[c]=c1[j+128];
    br[c]=b_hh[j]; bz[c]=b_hh[j+64]; bn[c]=b_hh[j+128];
  }

  // input side: K=16 against folded M1
  #pragma unroll
  for(int f=0; f<FF; f++){
    float av = a[f];
    #pragma unroll
    for(int c=0;c<16;c++){
      int j=c0+c;
      ar[c] += av*M1[j*FF+f];
      az[c] += av*M1[(j+64)*FF+f];
      an[c] += av*M1[(j+128)*FF+f];
    }
  }

  // hidden side: K=64 against w_hh
  const float4* hp = (const float4*)(hin + (size_t)node*HH);
  for(int q=0;q<16;q++){
    float4 hq = act ? hp[q] : make_float4(0.f,0.f,0.f,0.f);
    float hv[4]={hq.x,hq.y,hq.z,hq.w};
    #pragma unroll
    for(int i=0;i<4;i++){
      int k=4*q+i;
      #pragma unroll
      for(int c=0;c<16;c++){
        int j=c0+c;
        br[c] += hv[i]*w_hh[j*HH+k];
        bz[c] += hv[i]*w_hh[(j+64)*HH+k];
        bn[c] += hv[i]*w_hh[(j+128)*HH+k];
      }
    }
  }

  float ho[16];
  {
    const float4* hop = (const float4*)(hin + (size_t)node*HH + c0);
    #pragma unroll
    for(int q=0;q<4;q++){
      float4 v = act ? hop[q] : make_float4(0.f,0.f,0.f,0.f);
      ho[4*q+0]=v.x; ho[4*q+1]=v.y; ho[4*q+2]=v.z; ho[4*q+3]=v.w;
    }
  }

  if(act){
    float hnew[16];
    #pragma unroll
    for(int c=0;c<16;c++){
      float r = 1.f/(1.f + __expf(-(ar[c]+br[c])));
      float z = 1.f/(1.f + __expf(-(az[c]+bz[c])));
      float xv = an[c] + r*bn[c];
      float e = __expf(-2.f*fabsf(xv));
      float th = (1.f-e)/(1.f+e);
      th = copysignf(th, xv);
      hnew[c] = (1.f-z)*th + z*ho[c];
    }
    float4* op = (float4*)(hout + (size_t)node*HH + c0);
    #pragma unroll
    for(int q=0;q<4;q++)
      op[q] = make_float4(hnew[4*q+0],hnew[4*q+1],hnew[4*q+2],hnew[4*q+3]);
  }
}

__global__ void k_out(const float* __restrict__ h, const float* __restrict__ lin_w,
                      const float* __restrict__ lin_b, float* __restrict__ out, int N, int P){
  int n = blockIdx.x*blockDim.x + threadIdx.x;
  if(n>=N) return;
  float hv[HH];
  const float4* hp = (const float4*)(h + (size_t)n*HH);
  #pragma unroll
  for(int q=0;q<16;q++){ float4 v=hp[q]; hv[4*q]=v.x; hv[4*q+1]=v.y; hv[4*q+2]=v.z; hv[4*q+3]=v.w; }
  for(int p=0;p<P;p++){
    float acc = lin_b[p];
    #pragma unroll
    for(int k=0;k<HH;k++) acc += hv[k]*lin_w[p*HH+k];
    out[(size_t)p*N + n] = acc;
  }
}

extern "C" void kernel_launch(void* const* d_in, const int* in_sizes, int n_in,
                              void* d_out, int out_size, void* d_ws, size_t ws_size,
                              hipStream_t stream){
  const float* x     = (const float*)d_in[0];
  const float* gcn_w = (const float*)d_in[2];
  const float* gcn_b = (const float*)d_in[3];
  const float* w_ih  = (const float*)d_in[4];
  const float* w_hh  = (const float*)d_in[5];
  const float* b_ih  = (const float*)d_in[6];
  const float* b_hh  = (const float*)d_in[7];
  const float* lin_w = (const float*)d_in[8];
  const float* lin_b = (const float*)d_in[9];
  const int*   ei    = (const int*)d_in[10];
  const int E = in_sizes[10]/2;
  const int N = in_sizes[0]/(TT*FF);
  const int P = in_sizes[9];            // lin_b has P*O elements, O=1

  char* wsp = (char*)d_ws;
  auto alloc = [&](size_t bytes)->void*{ void* p = wsp; wsp += (bytes + 255) & ~(size_t)255; return p; };
  int*   deg      = (int*)  alloc((size_t)N*4);
  int*   counters = (int*)  alloc((size_t)N*4);
  int*   offsets  = (int*)  alloc((size_t)(N+1)*4);
  float* dinv     = (float*)alloc((size_t)N*4);
  int*   csr_src  = (int*)  alloc((size_t)E*4);
  float* csr_w    = (float*)alloc((size_t)E*4);
  float* agg      = (float*)alloc((size_t)TT*N*FF*4);
  float* hA       = (float*)alloc((size_t)N*HH*4);
  float* hB       = (float*)alloc((size_t)N*HH*4);
  float* M1       = (float*)alloc((size_t)192*FF*4);
  float* c1       = (float*)alloc((size_t)192*4);

  k_zero<<<(N+255)/256, 256, 0, stream>>>(deg, N);
  k_zero<<<(N+255)/256, 256, 0, stream>>>(counters, N);
  k_zero<<<2048, 256, 0, stream>>>((int*)hA, (long)N*HH);

  k_deg <<<(E+255)/256, 256, 0, stream>>>(ei, E, deg);
  k_dinv<<<(N+255)/256, 256, 0, stream>>>(deg, dinv, N);
  k_scan<<<1, 1024, 0, stream>>>(deg, offsets, N);
  k_fill<<<(E+255)/256, 256, 0, stream>>>(ei, E, dinv, offsets, counters, csr_src, csr_w);
  k_m1  <<<(192*FF+192+255)/256, 256, 0, stream>>>(gcn_w, gcn_b, w_ih, b_ih, M1, c1);

  k_agg <<<(N+3)/4, 256, 0, stream>>>(x, offsets, csr_src, csr_w, dinv, agg, N);

  for(int t=0; t<TT; t++){
    const float* hin = (t & 1) ? hB : hA;
    float*       hot = (t & 1) ? hA : hB;
    k_gru<<<(N+63)/64, 256, 0, stream>>>(agg + (size_t)t*N*FF, M1, c1, w_hh, b_hh, hin, hot, N);
  }
  // TT=24 (even) -> final state is in hA
  k_out<<<(N+255)/256, 256, 0, stream>>>(hA, lin_w, lin_b, (float*)d_out, N, P);
}

// Round 2
// 1226.244 us; speedup vs baseline: 7.8524x; 7.8524x over previous
//
#include <hip/hip_runtime.h>
#include <hip/hip_bf16.h>

#define TT 24
#define FF 16
#define HH 64
#define GG 192   // 3*HH

typedef __attribute__((ext_vector_type(4))) float f32x4;
typedef __attribute__((ext_vector_type(8))) short s16x8;

__device__ __forceinline__ ushort f2bf(float x){
  union{float f; unsigned u;} c; c.f = x;
  unsigned r = (c.u + 0x7fffu + ((c.u>>16)&1u)) >> 16;
  return (ushort)r;
}
__device__ __forceinline__ float bf2f(ushort h){
  union{unsigned u; float f;} c; c.u = ((unsigned)h)<<16; return c.f;
}
__device__ __forceinline__ float fast_rcp(float x){ return __builtin_amdgcn_rcpf(x); }
__device__ __forceinline__ float sigmoid_f(float x){
  return fast_rcp(1.0f + __expf(-x));
}
__device__ __forceinline__ float tanh_f(float x){
  float e = __expf(-2.0f * fabsf(x));
  float th = (1.0f - e) * fast_rcp(1.0f + e);
  return copysignf(th, x);
}

// ---------------- CSR build ----------------
__global__ void k_zero(int* __restrict__ p, long n){
  long i = (long)blockIdx.x*blockDim.x + threadIdx.x;
  long st = (long)gridDim.x*blockDim.x;
  for(; i<n; i+=st) p[i]=0;
}

__global__ void k_deg(const int* __restrict__ ei, int E, int* __restrict__ deg){
  int i = blockIdx.x*blockDim.x + threadIdx.x;
  if(i<E) atomicAdd(&deg[ei[E+i]], 1);   // dst = ei[E+i]
}

__global__ void k_dinv(const int* __restrict__ deg, float* __restrict__ dinv, int N){
  int i = blockIdx.x*blockDim.x + threadIdx.x;
  if(i<N) dinv[i] = rsqrtf((float)deg[i] + 1.0f);
}

__global__ __launch_bounds__(1024) void k_scan(const int* __restrict__ deg, int* __restrict__ offsets, int N){
  __shared__ int s[1024];
  int tid = threadIdx.x;
  int CH = (N + 1023) >> 10;
  int lo = tid*CH, hi = min(N, lo+CH);
  int sum=0;
  for(int j=lo;j<hi;j++) sum += deg[j];
  s[tid]=sum; __syncthreads();
  for(int o=1;o<1024;o<<=1){
    int v = 0;
    if(tid>=o) v = s[tid-o];
    __syncthreads();
    s[tid] += v;
    __syncthreads();
  }
  int run = s[tid]-sum;
  for(int j=lo;j<hi;j++){ offsets[j]=run; run += deg[j]; }
  if(tid==1023) offsets[N]=s[1023];
}

__global__ void k_fill(const int* __restrict__ ei, int E, const float* __restrict__ dinv,
                       const int* __restrict__ offsets, int* __restrict__ counters,
                       int* __restrict__ csr_src, float* __restrict__ csr_w){
  int i = blockIdx.x*blockDim.x + threadIdx.x;
  if(i>=E) return;
  int s = ei[i], d = ei[E+i];
  int slot = offsets[d] + atomicAdd(&counters[d], 1);
  csr_src[slot] = s;
  csr_w[slot]   = dinv[s]*dinv[d];
}

// ---------------- weight prep ----------------
// M1[j][f] = sum_h gcn_w[f][h]*w_ih[j][h]; c1[j] = b_ih[j] + sum_h gcn_b[h]*w_ih[j][h]
__global__ void k_m1(const float* __restrict__ gcn_w, const float* __restrict__ gcn_b,
                     const float* __restrict__ w_ih, const float* __restrict__ b_ih,
                     ushort* __restrict__ m1H, ushort* __restrict__ m1L, float* __restrict__ c1){
  int tid = blockIdx.x*blockDim.x + threadIdx.x;
  if(tid < GG*FF){
    int j = tid >> 4, f = tid & 15;
    float s = 0.f;
    for(int k=0;k<HH;k++) s += gcn_w[f*HH+k]*w_ih[j*HH+k];
    ushort h = f2bf(s);
    m1H[tid] = h;
    m1L[tid] = f2bf(s - bf2f(h));
  } else if (tid < GG*FF + GG){
    int j = tid - GG*FF;
    float s = b_ih[j];
    for(int k=0;k<HH;k++) s += gcn_b[k]*w_ih[j*HH+k];
    c1[j] = s;
  }
}

__global__ void k_split(const float* __restrict__ w, ushort* __restrict__ wH, ushort* __restrict__ wL, int n){
  int i = blockIdx.x*blockDim.x + threadIdx.x;
  if(i<n){
    float v = w[i];
    ushort h = f2bf(v);
    wH[i] = h;
    wL[i] = f2bf(v - bf2f(h));
  }
}

// ---------------- aggregation, t-per-XCD L2-blocked ----------------
// grid = 8 xcd * 3 t-per-xcd * NC chunks; block = 1024 = 16 waves = 16 nodes.
// wave per node; lane = (f = l&15, e4 = l>>4) -> 4 edges in flight.
__global__ __launch_bounds__(1024)
void k_agg2(const float* __restrict__ x, const int* __restrict__ offsets,
            const int* __restrict__ csr_src, const float* __restrict__ csr_w,
            const float* __restrict__ dinv, ushort* __restrict__ aggH, ushort* __restrict__ aggL,
            int N, int NC){
  int bid = blockIdx.x;
  int xcd = bid & 7, q = bid >> 3;
  int tl = q / NC, chunk = q - tl*NC;
  int t = xcd*3 + tl;
  int wv = threadIdx.x >> 6, l = threadIdx.x & 63;
  int n = chunk*16 + wv;
  if(n >= N) return;
  int f = l & 15, e4 = l >> 4;
  const float* xt = x + (size_t)t*N*FF;
  float acc = 0.f;
  int lo = offsets[n], hi = offsets[n+1];
  for(int j = lo + e4; j < hi; j += 4){
    int s = csr_src[j];
    acc += csr_w[j] * xt[(size_t)s*FF + f];
  }
  acc += __shfl_xor(acc, 16, 64);
  acc += __shfl_xor(acc, 32, 64);
  if(e4 == 0){
    float sn = dinv[n]; sn *= sn;
    acc += sn * xt[(size_t)n*FF + f];
    size_t o = ((size_t)t*N + n)*FF + f;
    ushort h = f2bf(acc);
    aggH[o] = h;
    aggL[o] = f2bf(acc - bf2f(h));
  }
}

// ---------------- persistent MFMA GRU over all 24 steps ----------------
// block = 256 threads = 4 waves; block owns 64 nodes; wave w owns channels [w*16, w*16+16).
// h state: bf16 hi/lo in double-buffered swizzled LDS. Weights: bf16 hi/lo B-frags in registers.
__global__ __launch_bounds__(256, 3)
void k_gru_all(const ushort* __restrict__ aggH, const ushort* __restrict__ aggL,
               const ushort* __restrict__ whhH, const ushort* __restrict__ whhL,
               const ushort* __restrict__ m1H,  const ushort* __restrict__ m1L,
               const float* __restrict__ c1, const float* __restrict__ bhh,
               float* __restrict__ hlast, int N){
  __shared__ ushort hb[2][2][64*64];   // [buf][hi/lo][node*64+ch] swizzled
  const int tid  = threadIdx.x;
  const int l    = tid & 63, w = tid >> 6;
  const int lrow = l & 15;    // A-row / B-col / D-col within tile
  const int lgrp = l >> 4;    // k-group for A/B; row-group for D
  const int ch   = w*16 + lrow;
  const int nbase = blockIdx.x * 64;

  // ---- load B-fragments (weight-stationary) ----
  // B[k][j] for tile: lane holds col j = lrow, k = ks*32 + lgrp*8 + 0..7 (contiguous)
  s16x8 bH[3][2], bL[3][2], mHf[3], mLf[3];
  #pragma unroll
  for(int g=0; g<3; g++){
    int j = g*HH + w*16 + lrow;
    #pragma unroll
    for(int ks=0; ks<2; ks++){
      int k0 = ks*32 + lgrp*8;
      bH[g][ks] = *(const s16x8*)(whhH + j*HH + k0);
      bL[g][ks] = *(const s16x8*)(whhL + j*HH + k0);
    }
    if(lgrp < 2){
      int k0 = lgrp*8;
      mHf[g] = *(const s16x8*)(m1H + j*FF + k0);
      mLf[g] = *(const s16x8*)(m1L + j*FF + k0);
    } else {
      mHf[g] = (s16x8){0,0,0,0,0,0,0,0};
      mLf[g] = (s16x8){0,0,0,0,0,0,0,0};
    }
  }

  // biases per output channel (D col = lrow -> ch)
  const float cbr = c1[ch]      + bhh[ch];
  const float cbz = c1[ch+HH]   + bhh[ch+HH];
  const float c1n = c1[ch+2*HH];
  const float bhn = bhh[ch+2*HH];

  float hreg[16];
  #pragma unroll
  for(int i=0;i<16;i++) hreg[i]=0.f;

  // zero h buffer 0 (both hi and lo planes): 8192 ushorts = 4096 dwords
  {
    uint* p = (uint*)&hb[0][0][0];
    for(int i=tid; i<4096; i+=256) p[i]=0u;
  }
  __syncthreads();

  for(int t=0; t<TT; t++){
    const int cur = t & 1, nxt = cur ^ 1;
    const ushort* aHt = aggH + (size_t)t*N*FF;
    const ushort* aLt = aggL + (size_t)t*N*FF;

    #pragma unroll
    for(int nt=0; nt<4; nt++){
      // A hidden fragments from LDS (swizzled)
      s16x8 ahH[2], ahL[2];
      const int r = nt*16 + lrow;
      #pragma unroll
      for(int ks=0; ks<2; ks++){
        int idx = (r*64 + ks*32 + lgrp*8) ^ ((r&7)<<3);
        ahH[ks] = *(const s16x8*)&hb[cur][0][idx];
        ahL[ks] = *(const s16x8*)&hb[cur][1][idx];
      }
      // A input fragments from global agg (K=16 zero-padded to 32)
      s16x8 agHf = (s16x8){0,0,0,0,0,0,0,0};
      s16x8 agLf = (s16x8){0,0,0,0,0,0,0,0};
      {
        int node = nbase + nt*16 + lrow;
        int nodec = min(node, N-1);
        if(lgrp < 2){
          size_t o = (size_t)nodec*FF + lgrp*8;
          agHf = *(const s16x8*)(aHt + o);
          agLf = *(const s16x8*)(aLt + o);
        }
      }

      f32x4 aR = {0.f,0.f,0.f,0.f}, aZ = {0.f,0.f,0.f,0.f};
      f32x4 aNi= {0.f,0.f,0.f,0.f}, aNh= {0.f,0.f,0.f,0.f};
      // hidden side: gates r,z merged with input acc later; n kept separate
      #pragma unroll
      for(int ks=0; ks<2; ks++){
        aR = __builtin_amdgcn_mfma_f32_16x16x32_bf16(ahH[ks], bH[0][ks], aR, 0,0,0);
        aR = __builtin_amdgcn_mfma_f32_16x16x32_bf16(ahL[ks], bH[0][ks], aR, 0,0,0);
        aR = __builtin_amdgcn_mfma_f32_16x16x32_bf16(ahH[ks], bL[0][ks], aR, 0,0,0);
        aZ = __builtin_amdgcn_mfma_f32_16x16x32_bf16(ahH[ks], bH[1][ks], aZ, 0,0,0);
        aZ = __builtin_amdgcn_mfma_f32_16x16x32_bf16(ahL[ks], bH[1][ks], aZ, 0,0,0);
        aZ = __builtin_amdgcn_mfma_f32_16x16x32_bf16(ahH[ks], bL[1][ks], aZ, 0,0,0);
        aNh= __builtin_amdgcn_mfma_f32_16x16x32_bf16(ahH[ks], bH[2][ks], aNh,0,0,0);
        aNh= __builtin_amdgcn_mfma_f32_16x16x32_bf16(ahL[ks], bH[2][ks], aNh,0,0,0);
        aNh= __builtin_amdgcn_mfma_f32_16x16x32_bf16(ahH[ks], bL[2][ks], aNh,0,0,0);
      }
      // input side
      aR  = __builtin_amdgcn_mfma_f32_16x16x32_bf16(agHf, mHf[0], aR, 0,0,0);
      aR  = __builtin_amdgcn_mfma_f32_16x16x32_bf16(agLf, mHf[0], aR, 0,0,0);
      aR  = __builtin_amdgcn_mfma_f32_16x16x32_bf16(agHf, mLf[0], aR, 0,0,0);
      aZ  = __builtin_amdgcn_mfma_f32_16x16x32_bf16(agHf, mHf[1], aZ, 0,0,0);
      aZ  = __builtin_amdgcn_mfma_f32_16x16x32_bf16(agLf, mHf[1], aZ, 0,0,0);
      aZ  = __builtin_amdgcn_mfma_f32_16x16x32_bf16(agHf, mLf[1], aZ, 0,0,0);
      aNi = __builtin_amdgcn_mfma_f32_16x16x32_bf16(agHf, mHf[2], aNi,0,0,0);
      aNi = __builtin_amdgcn_mfma_f32_16x16x32_bf16(agLf, mHf[2], aNi,0,0,0);
      aNi = __builtin_amdgcn_mfma_f32_16x16x32_bf16(agHf, mLf[2], aNi,0,0,0);

      // epilogue: D row = lgrp*4 + i, col = lrow
      #pragma unroll
      for(int i=0;i<4;i++){
        float r_ = sigmoid_f(aR[i] + cbr);
        float z_ = sigmoid_f(aZ[i] + cbz);
        float nn = tanh_f(aNi[i] + c1n + r_*(aNh[i] + bhn));
        int hidx = nt*4 + i;
        float hp = hreg[hidx];
        float hn = nn + z_*(hp - nn);
        hreg[hidx] = hn;
        int noderow = nt*16 + lgrp*4 + i;
        int idx = (noderow*64 + ch) ^ ((noderow&7)<<3);
        ushort hiw = f2bf(hn);
        hb[nxt][0][idx] = hiw;
        hb[nxt][1][idx] = f2bf(hn - bf2f(hiw));
      }
    }
    __syncthreads();
  }

  // write final h (fp32)
  #pragma unroll
  for(int hidx=0; hidx<16; hidx++){
    int nt = hidx >> 2, i = hidx & 3;
    int node = nbase + nt*16 + lgrp*4 + i;
    if(node < N) hlast[(size_t)node*HH + ch] = hreg[hidx];
  }
}

// ---------------- output head ----------------
__global__ void k_out(const float* __restrict__ h, const float* __restrict__ lin_w,
                      const float* __restrict__ lin_b, float* __restrict__ out, int N, int P){
  int n = blockIdx.x*blockDim.x + threadIdx.x;
  if(n>=N) return;
  float hv[HH];
  const float4* hp = (const float4*)(h + (size_t)n*HH);
  #pragma unroll
  for(int q=0;q<16;q++){ float4 v=hp[q]; hv[4*q]=v.x; hv[4*q+1]=v.y; hv[4*q+2]=v.z; hv[4*q+3]=v.w; }
  for(int p=0;p<P;p++){
    float acc = lin_b[p];
    #pragma unroll
    for(int k=0;k<HH;k++) acc += hv[k]*lin_w[p*HH+k];
    out[(size_t)p*N + n] = acc;
  }
}

extern "C" void kernel_launch(void* const* d_in, const int* in_sizes, int n_in,
                              void* d_out, int out_size, void* d_ws, size_t ws_size,
                              hipStream_t stream){
  const float* x     = (const float*)d_in[0];
  const float* gcn_w = (const float*)d_in[2];
  const float* gcn_b = (const float*)d_in[3];
  const float* w_ih  = (const float*)d_in[4];
  const float* w_hh  = (const float*)d_in[5];
  const float* b_ih  = (const float*)d_in[6];
  const float* b_hh  = (const float*)d_in[7];
  const float* lin_w = (const float*)d_in[8];
  const float* lin_b = (const float*)d_in[9];
  const int*   ei    = (const int*)d_in[10];
  const int E = in_sizes[10]/2;
  const int N = in_sizes[0]/(TT*FF);
  const int P = in_sizes[9];

  char* wsp = (char*)d_ws;
  auto alloc = [&](size_t bytes)->void*{ void* p = wsp; wsp += (bytes + 255) & ~(size_t)255; return p; };
  int*    deg      = (int*)   alloc((size_t)N*4);
  int*    counters = (int*)   alloc((size_t)N*4);
  int*    offsets  = (int*)   alloc((size_t)(N+1)*4);
  float*  dinv     = (float*) alloc((size_t)N*4);
  int*    csr_src  = (int*)   alloc((size_t)E*4);
  float*  csr_w    = (float*) alloc((size_t)E*4);
  ushort* aggH     = (ushort*)alloc((size_t)TT*N*FF*2);
  ushort* aggL     = (ushort*)alloc((size_t)TT*N*FF*2);
  float*  hlast    = (float*) alloc((size_t)N*HH*4);
  ushort* m1H      = (ushort*)alloc((size_t)GG*FF*2);
  ushort* m1L      = (ushort*)alloc((size_t)GG*FF*2);
  float*  c1       = (float*) alloc((size_t)GG*4);
  ushort* whhH     = (ushort*)alloc((size_t)GG*HH*2);
  ushort* whhL     = (ushort*)alloc((size_t)GG*HH*2);

  k_zero<<<(N+255)/256, 256, 0, stream>>>(deg, N);
  k_zero<<<(N+255)/256, 256, 0, stream>>>(counters, N);

  k_deg <<<(E+255)/256, 256, 0, stream>>>(ei, E, deg);
  k_dinv<<<(N+255)/256, 256, 0, stream>>>(deg, dinv, N);
  k_scan<<<1, 1024, 0, stream>>>(deg, offsets, N);
  k_fill<<<(E+255)/256, 256, 0, stream>>>(ei, E, dinv, offsets, counters, csr_src, csr_w);
  k_m1  <<<(GG*FF+GG+255)/256, 256, 0, stream>>>(gcn_w, gcn_b, w_ih, b_ih, m1H, m1L, c1);
  k_split<<<(GG*HH+255)/256, 256, 0, stream>>>(w_hh, whhH, whhL, GG*HH);

  const int NC = (N + 15) / 16;
  k_agg2<<<8*3*NC, 1024, 0, stream>>>(x, offsets, csr_src, csr_w, dinv, aggH, aggL, N, NC);

  k_gru_all<<<(N+63)/64, 256, 0, stream>>>(aggH, aggL, whhH, whhL, m1H, m1L, c1, b_hh, hlast, N);

  k_out<<<(N+255)/256, 256, 0, stream>>>(hlast, lin_w, lin_b, (float*)d_out, N, P);
}

// Round 3
// 886.917 us; speedup vs baseline: 10.8567x; 1.3826x over previous
//
#include <hip/hip_runtime.h>
#include <hip/hip_bf16.h>

#define TT 24
#define FF 16
#define HH 64
#define GG 192   // 3*HH

typedef __attribute__((ext_vector_type(4))) float f32x4;
typedef __attribute__((ext_vector_type(8))) short s16x8;

__device__ __forceinline__ ushort f2bf(float x){
  union{float f; unsigned u;} c; c.f = x;
  unsigned r = (c.u + 0x7fffu + ((c.u>>16)&1u)) >> 16;
  return (ushort)r;
}
__device__ __forceinline__ float bf2f(ushort h){
  union{unsigned u; float f;} c; c.u = ((unsigned)h)<<16; return c.f;
}
__device__ __forceinline__ float fast_rcp(float x){ return __builtin_amdgcn_rcpf(x); }
__device__ __forceinline__ float sigmoid_f(float x){
  return fast_rcp(1.0f + __expf(-x));
}
__device__ __forceinline__ float tanh_f(float x){
  float e = __expf(-2.0f * fabsf(x));
  float th = (1.0f - e) * fast_rcp(1.0f + e);
  return copysignf(th, x);
}

// ---------------- CSR build ----------------
__global__ void k_zero(int* __restrict__ p, long n){
  long i = (long)blockIdx.x*blockDim.x + threadIdx.x;
  long st = (long)gridDim.x*blockDim.x;
  for(; i<n; i+=st) p[i]=0;
}

__global__ void k_deg(const int* __restrict__ ei, int E, int* __restrict__ deg){
  int i = blockIdx.x*blockDim.x + threadIdx.x;
  if(i<E) atomicAdd(&deg[ei[E+i]], 1);   // dst = ei[E+i]
}

__global__ void k_dinv(const int* __restrict__ deg, float* __restrict__ dinv, int N){
  int i = blockIdx.x*blockDim.x + threadIdx.x;
  if(i<N) dinv[i] = rsqrtf((float)deg[i] + 1.0f);
}

__global__ __launch_bounds__(1024) void k_scan(const int* __restrict__ deg, int* __restrict__ offsets, int N){
  __shared__ int s[1024];
  int tid = threadIdx.x;
  int CH = (N + 1023) >> 10;
  int lo = tid*CH, hi = min(N, lo+CH);
  int sum=0;
  for(int j=lo;j<hi;j++) sum += deg[j];
  s[tid]=sum; __syncthreads();
  for(int o=1;o<1024;o<<=1){
    int v = 0;
    if(tid>=o) v = s[tid-o];
    __syncthreads();
    s[tid] += v;
    __syncthreads();
  }
  int run = s[tid]-sum;
  for(int j=lo;j<hi;j++){ offsets[j]=run; run += deg[j]; }
  if(tid==1023) offsets[N]=s[1023];
}

__global__ void k_fill(const int* __restrict__ ei, int E, const float* __restrict__ dinv,
                       const int* __restrict__ offsets, int* __restrict__ counters,
                       int2* __restrict__ csr2){
  int i = blockIdx.x*blockDim.x + threadIdx.x;
  if(i>=E) return;
  int s = ei[i], d = ei[E+i];
  int slot = offsets[d] + atomicAdd(&counters[d], 1);
  csr2[slot] = make_int2(s, __float_as_int(dinv[s]*dinv[d]));
}

// ---------------- weight prep ----------------
__global__ void k_m1(const float* __restrict__ gcn_w, const float* __restrict__ gcn_b,
                     const float* __restrict__ w_ih, const float* __restrict__ b_ih,
                     ushort* __restrict__ m1H, ushort* __restrict__ m1L, float* __restrict__ c1){
  int tid = blockIdx.x*blockDim.x + threadIdx.x;
  if(tid < GG*FF){
    int j = tid >> 4, f = tid & 15;
    float s = 0.f;
    for(int k=0;k<HH;k++) s += gcn_w[f*HH+k]*w_ih[j*HH+k];
    ushort h = f2bf(s);
    m1H[tid] = h;
    m1L[tid] = f2bf(s - bf2f(h));
  } else if (tid < GG*FF + GG){
    int j = tid - GG*FF;
    float s = b_ih[j];
    for(int k=0;k<HH;k++) s += gcn_b[k]*w_ih[j*HH+k];
    c1[j] = s;
  }
}

__global__ void k_split(const float* __restrict__ w, ushort* __restrict__ wH, ushort* __restrict__ wL, int n){
  int i = blockIdx.x*blockDim.x + threadIdx.x;
  if(i<n){
    float v = w[i];
    ushort h = f2bf(v);
    wH[i] = h;
    wL[i] = f2bf(v - bf2f(h));
  }
}

// ---------------- aggregation: t-per-XCD, float4 lanes, 32 edges/round ----------------
// grid = 8 xcd * 3 tl * NC chunks; block = 1024 = 16 waves = 16 nodes.
// wave per (node,t); lane = (f4 = l&3 -> float4 slice, e = l>>2 -> 16 edge slots);
// predicated 2-way unroll => 32 edges (avg degree) per round, 2 csr + 2 gathers in flight.
__global__ __launch_bounds__(1024)
void k_agg3(const float* __restrict__ x, const int* __restrict__ offsets,
            const int2* __restrict__ csr2, const float* __restrict__ dinv,
            ushort* __restrict__ aggH, ushort* __restrict__ aggL,
            int N, int NC){
  int bid = blockIdx.x;
  int xcd = bid & 7, q = bid >> 3;
  int tl = q / NC, chunk = q - tl*NC;
  int t = xcd*3 + tl;
  int wv = threadIdx.x >> 6, l = threadIdx.x & 63;
  int n = chunk*16 + wv;
  if(n >= N) return;
  int f4 = l & 3, e = l >> 2;
  const float4* xt4 = (const float4*)(x + (size_t)t*N*FF);
  float4 a = make_float4(0.f,0.f,0.f,0.f);
  int lo = offsets[n], hi = offsets[n+1];
  for(int j = lo + e; j < hi; j += 32){
    int jj1 = j + 16;
    bool ok1 = jj1 < hi;
    int2 c0 = csr2[j];
    int2 c1 = csr2[ok1 ? jj1 : j];
    float4 v0 = xt4[c0.x*4 + f4];
    float4 v1 = xt4[c1.x*4 + f4];
    float w0 = __int_as_float(c0.y);
    float w1 = ok1 ? __int_as_float(c1.y) : 0.f;
    a.x += w0*v0.x; a.y += w0*v0.y; a.z += w0*v0.z; a.w += w0*v0.w;
    a.x += w1*v1.x; a.y += w1*v1.y; a.z += w1*v1.z; a.w += w1*v1.w;
  }
  #pragma unroll
  for(int m = 4; m <= 32; m <<= 1){
    a.x += __shfl_xor(a.x, m, 64);
    a.y += __shfl_xor(a.y, m, 64);
    a.z += __shfl_xor(a.z, m, 64);
    a.w += __shfl_xor(a.w, m, 64);
  }
  if(e == 0){
    float sn = dinv[n]; sn *= sn;
    float4 xs = xt4[n*4 + f4];
    a.x += sn*xs.x; a.y += sn*xs.y; a.z += sn*xs.z; a.w += sn*xs.w;
    size_t o = ((size_t)t*N + n)*FF + f4*4;
    ushort4 h, lw;
    h.x = f2bf(a.x); lw.x = f2bf(a.x - bf2f(h.x));
    h.y = f2bf(a.y); lw.y = f2bf(a.y - bf2f(h.y));
    h.z = f2bf(a.z); lw.z = f2bf(a.z - bf2f(h.z));
    h.w = f2bf(a.w); lw.w = f2bf(a.w - bf2f(h.w));
    *(ushort4*)(aggH + o) = h;
    *(ushort4*)(aggL + o) = lw;
  }
}

// ---------------- persistent MFMA GRU over all 24 steps ----------------
__global__ __launch_bounds__(256, 3)
void k_gru_all(const ushort* __restrict__ aggH, const ushort* __restrict__ aggL,
               const ushort* __restrict__ whhH, const ushort* __restrict__ whhL,
               const ushort* __restrict__ m1H,  const ushort* __restrict__ m1L,
               const float* __restrict__ c1, const float* __restrict__ bhh,
               float* __restrict__ hlast, int N){
  __shared__ ushort hb[2][2][64*64];   // [buf][hi/lo][node*64+ch] swizzled
  const int tid  = threadIdx.x;
  const int l    = tid & 63, w = tid >> 6;
  const int lrow = l & 15;
  const int lgrp = l >> 4;
  const int ch   = w*16 + lrow;
  const int nbase = blockIdx.x * 64;

  s16x8 bH[3][2], bL[3][2], mHf[3], mLf[3];
  #pragma unroll
  for(int g=0; g<3; g++){
    int j = g*HH + w*16 + lrow;
    #pragma unroll
    for(int ks=0; ks<2; ks++){
      int k0 = ks*32 + lgrp*8;
      bH[g][ks] = *(const s16x8*)(whhH + j*HH + k0);
      bL[g][ks] = *(const s16x8*)(whhL + j*HH + k0);
    }
    if(lgrp < 2){
      int k0 = lgrp*8;
      mHf[g] = *(const s16x8*)(m1H + j*FF + k0);
      mLf[g] = *(const s16x8*)(m1L + j*FF + k0);
    } else {
      mHf[g] = (s16x8){0,0,0,0,0,0,0,0};
      mLf[g] = (s16x8){0,0,0,0,0,0,0,0};
    }
  }

  const float cbr = c1[ch]      + bhh[ch];
  const float cbz = c1[ch+HH]   + bhh[ch+HH];
  const float c1n = c1[ch+2*HH];
  const float bhn = bhh[ch+2*HH];

  float hreg[16];
  #pragma unroll
  for(int i=0;i<16;i++) hreg[i]=0.f;

  {
    uint* p = (uint*)&hb[0][0][0];
    for(int i=tid; i<4096; i+=256) p[i]=0u;
  }
  __syncthreads();

  for(int t=0; t<TT; t++){
    const int cur = t & 1, nxt = cur ^ 1;
    const ushort* aHt = aggH + (size_t)t*N*FF;
    const ushort* aLt = aggL + (size_t)t*N*FF;

    #pragma unroll
    for(int nt=0; nt<4; nt++){
      s16x8 ahH[2], ahL[2];
      const int r = nt*16 + lrow;
      #pragma unroll
      for(int ks=0; ks<2; ks++){
        int idx = (r*64 + ks*32 + lgrp*8) ^ ((r&7)<<3);
        ahH[ks] = *(const s16x8*)&hb[cur][0][idx];
        ahL[ks] = *(const s16x8*)&hb[cur][1][idx];
      }
      s16x8 agHf = (s16x8){0,0,0,0,0,0,0,0};
      s16x8 agLf = (s16x8){0,0,0,0,0,0,0,0};
      {
        int node = nbase + nt*16 + lrow;
        int nodec = min(node, N-1);
        if(lgrp < 2){
          size_t o = (size_t)nodec*FF + lgrp*8;
          agHf = *(const s16x8*)(aHt + o);
          agLf = *(const s16x8*)(aLt + o);
        }
      }

      f32x4 aR = {0.f,0.f,0.f,0.f}, aZ = {0.f,0.f,0.f,0.f};
      f32x4 aNi= {0.f,0.f,0.f,0.f}, aNh= {0.f,0.f,0.f,0.f};
      #pragma unroll
      for(int ks=0; ks<2; ks++){
        aR = __builtin_amdgcn_mfma_f32_16x16x32_bf16(ahH[ks], bH[0][ks], aR, 0,0,0);
        aR = __builtin_amdgcn_mfma_f32_16x16x32_bf16(ahL[ks], bH[0][ks], aR, 0,0,0);
        aR = __builtin_amdgcn_mfma_f32_16x16x32_bf16(ahH[ks], bL[0][ks], aR, 0,0,0);
        aZ = __builtin_amdgcn_mfma_f32_16x16x32_bf16(ahH[ks], bH[1][ks], aZ, 0,0,0);
        aZ = __builtin_amdgcn_mfma_f32_16x16x32_bf16(ahL[ks], bH[1][ks], aZ, 0,0,0);
        aZ = __builtin_amdgcn_mfma_f32_16x16x32_bf16(ahH[ks], bL[1][ks], aZ, 0,0,0);
        aNh= __builtin_amdgcn_mfma_f32_16x16x32_bf16(ahH[ks], bH[2][ks], aNh,0,0,0);
        aNh= __builtin_amdgcn_mfma_f32_16x16x32_bf16(ahL[ks], bH[2][ks], aNh,0,0,0);
        aNh= __builtin_amdgcn_mfma_f32_16x16x32_bf16(ahH[ks], bL[2][ks], aNh,0,0,0);
      }
      aR  = __builtin_amdgcn_mfma_f32_16x16x32_bf16(agHf, mHf[0], aR, 0,0,0);
      aR  = __builtin_amdgcn_mfma_f32_16x16x32_bf16(agLf, mHf[0], aR, 0,0,0);
      aR  = __builtin_amdgcn_mfma_f32_16x16x32_bf16(agHf, mLf[0], aR, 0,0,0);
      aZ  = __builtin_amdgcn_mfma_f32_16x16x32_bf16(agHf, mHf[1], aZ, 0,0,0);
      aZ  = __builtin_amdgcn_mfma_f32_16x16x32_bf16(agLf, mHf[1], aZ, 0,0,0);
      aZ  = __builtin_amdgcn_mfma_f32_16x16x32_bf16(agHf, mLf[1], aZ, 0,0,0);
      aNi = __builtin_amdgcn_mfma_f32_16x16x32_bf16(agHf, mHf[2], aNi,0,0,0);
      aNi = __builtin_amdgcn_mfma_f32_16x16x32_bf16(agLf, mHf[2], aNi,0,0,0);
      aNi = __builtin_amdgcn_mfma_f32_16x16x32_bf16(agHf, mLf[2], aNi,0,0,0);

      #pragma unroll
      for(int i=0;i<4;i++){
        float r_ = sigmoid_f(aR[i] + cbr);
        float z_ = sigmoid_f(aZ[i] + cbz);
        float nn = tanh_f(aNi[i] + c1n + r_*(aNh[i] + bhn));
        int hidx = nt*4 + i;
        float hp = hreg[hidx];
        float hn = nn + z_*(hp - nn);
        hreg[hidx] = hn;
        int noderow = nt*16 + lgrp*4 + i;
        int idx = (noderow*64 + ch) ^ ((noderow&7)<<3);
        ushort hiw = f2bf(hn);
        hb[nxt][0][idx] = hiw;
        hb[nxt][1][idx] = f2bf(hn - bf2f(hiw));
      }
    }
    __syncthreads();
  }

  #pragma unroll
  for(int hidx=0; hidx<16; hidx++){
    int nt = hidx >> 2, i = hidx & 3;
    int node = nbase + nt*16 + lgrp*4 + i;
    if(node < N) hlast[(size_t)node*HH + ch] = hreg[hidx];
  }
}

// ---------------- output head ----------------
__global__ void k_out(const float* __restrict__ h, const float* __restrict__ lin_w,
                      const float* __restrict__ lin_b, float* __restrict__ out, int N, int P){
  int n = blockIdx.x*blockDim.x + threadIdx.x;
  if(n>=N) return;
  float hv[HH];
  const float4* hp = (const float4*)(h + (size_t)n*HH);
  #pragma unroll
  for(int q=0;q<16;q++){ float4 v=hp[q]; hv[4*q]=v.x; hv[4*q+1]=v.y; hv[4*q+2]=v.z; hv[4*q+3]=v.w; }
  for(int p=0;p<P;p++){
    float acc = lin_b[p];
    #pragma unroll
    for(int k=0;k<HH;k++) acc += hv[k]*lin_w[p*HH+k];
    out[(size_t)p*N + n] = acc;
  }
}

extern "C" void kernel_launch(void* const* d_in, const int* in_sizes, int n_in,
                              void* d_out, int out_size, void* d_ws, size_t ws_size,
                              hipStream_t stream){
  const float* x     = (const float*)d_in[0];
  const float* gcn_w = (const float*)d_in[2];
  const float* gcn_b = (const float*)d_in[3];
  const float* w_ih  = (const float*)d_in[4];
  const float* w_hh  = (const float*)d_in[5];
  const float* b_ih  = (const float*)d_in[6];
  const float* b_hh  = (const float*)d_in[7];
  const float* lin_w = (const float*)d_in[8];
  const float* lin_b = (const float*)d_in[9];
  const int*   ei    = (const int*)d_in[10];
  const int E = in_sizes[10]/2;
  const int N = in_sizes[0]/(TT*FF);
  const int P = in_sizes[9];

  char* wsp = (char*)d_ws;
  auto alloc = [&](size_t bytes)->void*{ void* p = wsp; wsp += (bytes + 255) & ~(size_t)255; return p; };
  int*    deg      = (int*)   alloc((size_t)N*4);
  int*    counters = (int*)   alloc((size_t)N*4);
  int*    offsets  = (int*)   alloc((size_t)(N+1)*4);
  float*  dinv     = (float*) alloc((size_t)N*4);
  int2*   csr2     = (int2*)  alloc((size_t)E*8);
  ushort* aggH     = (ushort*)alloc((size_t)TT*N*FF*2);
  ushort* aggL     = (ushort*)alloc((size_t)TT*N*FF*2);
  float*  hlast    = (float*) alloc((size_t)N*HH*4);
  ushort* m1H      = (ushort*)alloc((size_t)GG*FF*2);
  ushort* m1L      = (ushort*)alloc((size_t)GG*FF*2);
  float*  c1       = (float*) alloc((size_t)GG*4);
  ushort* whhH     = (ushort*)alloc((size_t)GG*HH*2);
  ushort* whhL     = (ushort*)alloc((size_t)GG*HH*2);

  k_zero<<<(N+255)/256, 256, 0, stream>>>(deg, N);
  k_zero<<<(N+255)/256, 256, 0, stream>>>(counters, N);

  k_deg <<<(E+255)/256, 256, 0, stream>>>(ei, E, deg);
  k_dinv<<<(N+255)/256, 256, 0, stream>>>(deg, dinv, N);
  k_scan<<<1, 1024, 0, stream>>>(deg, offsets, N);
  k_fill<<<(E+255)/256, 256, 0, stream>>>(ei, E, dinv, offsets, counters, csr2);
  k_m1  <<<(GG*FF+GG+255)/256, 256, 0, stream>>>(gcn_w, gcn_b, w_ih, b_ih, m1H, m1L, c1);
  k_split<<<(GG*HH+255)/256, 256, 0, stream>>>(w_hh, whhH, whhL, GG*HH);

  const int NC = (N + 15) / 16;
  k_agg3<<<8*3*NC, 1024, 0, stream>>>(x, offsets, csr2, dinv, aggH, aggL, N, NC);

  k_gru_all<<<(N+63)/64, 256, 0, stream>>>(aggH, aggL, whhH, whhL, m1H, m1L, c1, b_hh, hlast, N);

  k_out<<<(N+255)/256, 256, 0, stream>>>(hlast, lin_w, lin_b, (float*)d_out, N, P);
}